// Round 16
// baseline (751.047 us; speedup 1.0000x reference)
//
#include <hip/hip_runtime.h>
#include <math.h>
#include <stdint.h>

#define N_NODES_C 50000
#define N_GRAPHS_C 64
#define HDIM 128

typedef short bf16x8 __attribute__((ext_vector_type(8)));
typedef short shortx4 __attribute__((ext_vector_type(4)));
typedef float floatx4 __attribute__((ext_vector_type(4)));
typedef _Float16 halfx4 __attribute__((ext_vector_type(4)));

// f32 -> bf16 round-to-nearest-even
__device__ __forceinline__ short cvt_rn(float x) {
    union { float f; unsigned u; } a; a.f = x;
    unsigned r = a.u + 0x7FFFu + ((a.u >> 16) & 1u);
    return (short)(r >> 16);
}

__device__ __forceinline__ float b2f(short s) {
    union { unsigned u; float f; } x; x.u = ((unsigned)(unsigned short)s) << 16;
    return x.f;
}

// async global->LDS copy, 16 B per lane, LDS dest = wave-uniform base + lane*16
__device__ __forceinline__ void gld_lds16(const void* gsrc, void* ldst) {
    __builtin_amdgcn_global_load_lds(
        (const __attribute__((address_space(1))) unsigned int*)gsrc,
        (__attribute__((address_space(3))) unsigned int*)ldst,
        16, 0, 0);
}

// ============ x f32 -> bf16 pre-convert (R13) ============
__global__ __launch_bounds__(256) void xcvt_kernel(
    const float* __restrict__ x, short* __restrict__ xb, long nq)
{
    long i = (long)blockIdx.x * 256 + threadIdx.x;
    long stride = (long)gridDim.x * 256;
    for (; i < nq; i += stride) {
        float4 f = *(const float4*)(x + i * 4);
        *(shortx4*)(xb + i * 4) =
            (shortx4){cvt_rn(f.x), cvt_rn(f.y), cvt_rn(f.z), cvt_rn(f.w)};
    }
}

// ============ MFMA GEMM, single bf16 plane ============
// R16 modes:
//   DB=1 (layer-1 QKV, K=512): TM=128 double-buffer 2-phase, 32 KB LDS,
//     (256,3) — R14-measured best (84 us); one __syncthreads per k-tile.
//   DB=2 "ONESHOT" (all K=128 GEMMs): TM=64, stage the ENTIRE K extent
//     (4 k-tiles, NB=4 buffers, 48 KB LDS) with 12 back-to-back
//     global_load_lds per wave, ONE __syncthreads, then all MFMAs.
//     Barriers 8 -> 1 per block; staging latency fully overlapped.
//   DB=0 retained (unused default single-buffer path).
// bf16 granule XOR-swizzle both sides; XCD-bijective block swizzle (frozen).
// mode 0: cols [0,128) -> fp16 Q (ld 128); cols [128,640) -> fp16 KV (ld 512)
// mode 2: Chi = bf16 relu(v + bias)            (ldc = 128)
// mode 3: Chi = bf16 relu(gate*v+bias + (1-gate)*prev_hi)
#define GBM 128
#define GBN 128
#define GBK 32

template<int DB, int TM>
__global__ __launch_bounds__(256, TM == 64 ? 4 : 3) void gemm_planes(
    const short* __restrict__ Ahi, int lda,
    const short* __restrict__ Bhi, int ldbt,
    const float* __restrict__ bias,
    _Float16* __restrict__ Qh, short* __restrict__ Chi,
    int M, int Ntot, int K,
    int mode, const float* __restrict__ skipGate,
    const short* __restrict__ Phi)
{
    constexpr int ASZ = TM * GBK;                              // shorts / buffer
    constexpr int BSZ = GBN * GBK;
    constexpr int NB  = (DB == 1) ? 2 : (DB == 2 ? 4 : 1);     // LDS buffers
    constexpr int NI  = TM / 32;                               // A fragments/wave
    constexpr int WR  = TM / 2;                                // rows per wm group
    __shared__ __align__(16) short AsH[NB * ASZ];
    __shared__ __align__(16) short BsH[NB * BSZ];

    const int t = threadIdx.x;
    const int lane = t & 63;
    const int wave = t >> 6;
    const int wm = wave & 1, wn = wave >> 1;
    const int quad = lane >> 4, l15 = lane & 15;

    // XCD-bijective chunked swizzle (valid for any nwg), column-fastest decode
    const int nwg = gridDim.x, bid0 = blockIdx.x;
    const int qq = nwg >> 3, rr = nwg & 7;
    const int xcd = bid0 & 7, idx = bid0 >> 3;
    const int swz = (xcd < rr ? xcd * (qq + 1)
                              : rr * (qq + 1) + (xcd - rr) * qq) + idx;
    const int ncb = (Ntot + GBN - 1) / GBN;
    const long row0 = (long)(swz / ncb) * TM;
    const long col0 = (long)(swz % ncb) * GBN;

    floatx4 acc[NI][4];
    #pragma unroll
    for (int i = 0; i < NI; ++i)
        #pragma unroll
        for (int j = 0; j < 4; ++j)
            acc[i][j] = (floatx4){0.f, 0.f, 0.f, 0.f};

    const int nkt = K / GBK;

    auto stage = [&](int buf, int k0) {
        int r16 = lane >> 2, g4 = lane & 3;
        int gs = (g4 ^ ((r16 >> 1) & 3)) * 8;       // granule swizzle (src side)
        #pragma unroll
        for (int cc = 0; cc < TM / 64; ++cc) {      // 2 chunks (TM=128) / 1 (TM=64)
            int ch = wave * (TM / 64) + cc;
            long gr = row0 + ch * 16 + r16;
            if (gr > M - 1) gr = M - 1;
            gld_lds16(Ahi + gr * lda + k0 + gs, AsH + buf * ASZ + ch * 512);
        }
        #pragma unroll
        for (int cc = 0; cc < 2; ++cc) {
            int ch = wave * 2 + cc;
            long gc = col0 + ch * 16 + r16;
            if (gc > Ntot - 1) gc = Ntot - 1;
            gld_lds16(Bhi + gc * ldbt + k0 + gs, BsH + buf * BSZ + ch * 512);
        }
    };

    auto compute = [&](int buf) {
        bf16x8 aH[NI], bH[4];
        #pragma unroll
        for (int i = 0; i < NI; ++i) {
            int row = wm * WR + i * 16 + l15;
            int off = buf * ASZ + row * 32 + ((quad ^ ((row >> 1) & 3)) * 8);
            aH[i] = *(const bf16x8*)&AsH[off];
        }
        #pragma unroll
        for (int j = 0; j < 4; ++j) {
            int row = wn * 64 + j * 16 + l15;
            int off = buf * BSZ + row * 32 + ((quad ^ ((row >> 1) & 3)) * 8);
            bH[j] = *(const bf16x8*)&BsH[off];
        }
        #pragma unroll
        for (int i = 0; i < NI; ++i)
            #pragma unroll
            for (int j = 0; j < 4; ++j)
                acc[i][j] = __builtin_amdgcn_mfma_f32_16x16x32_bf16(aH[i], bH[j], acc[i][j], 0, 0, 0);
    };

    if constexpr (DB == 1) {
        stage(0, 0);
        int cur = 0;
        for (int kt = 0; kt < nkt; ++kt) {
            __syncthreads();   // own stage landed; all waves done with cur^1
            if (kt + 1 < nkt) stage(cur ^ 1, (kt + 1) * GBK);
            compute(cur);
            cur ^= 1;
        }
    } else if constexpr (DB == 2) {
        // ONESHOT: entire K extent staged at once (requires nkt <= NB)
        #pragma unroll
        for (int kt = 0; kt < 4; ++kt) stage(kt, kt * GBK);
        __syncthreads();       // single barrier: all 4 k-tiles in LDS
        #pragma unroll
        for (int kt = 0; kt < 4; ++kt) compute(kt);
    } else {
        for (int kt = 0; kt < nkt; ++kt) {
            stage(0, kt * GBK);
            __syncthreads();
            compute(0);
            __syncthreads();
        }
    }

    float gate = 0.f;
    if (mode == 3) gate = 1.f / (1.f + __expf(-skipGate[0]));
    _Float16* kvout = (_Float16*)Chi;   // mode 0 fp16 KV destination

    #pragma unroll
    for (int i = 0; i < NI; ++i) {
        #pragma unroll
        for (int r4 = 0; r4 < 4; ++r4) {
            long grow = row0 + wm * WR + i * 16 + quad * 4 + r4;
            if (grow >= M) continue;
            #pragma unroll
            for (int j = 0; j < 4; ++j) {
                long gcol = col0 + wn * 64 + j * 16 + l15;
                if (gcol >= Ntot) continue;
                float v = acc[i][j][r4];
                if (bias) v += bias[gcol];
                if (mode == 0) {
                    if (gcol < 128) Qh[grow * 128 + gcol] = (_Float16)v;
                    else kvout[grow * 512 + (gcol - 128)] = (_Float16)v;
                } else {
                    if (mode == 3) {
                        float pv = b2f(Phi[grow * 128 + gcol]);
                        v = gate * v + (1.f - gate) * pv;
                    }
                    v = fmaxf(v, 0.f);
                    Chi[grow * 128 + gcol] = cvt_rn(v);
                }
            }
        }
    }
}

// ============ build fused WbigT[640, F] bf16 plane + bias640 + WaT ============
__global__ __launch_bounds__(256) void build_wbigT_p(
    const float* __restrict__ Wq, const float* __restrict__ bq,
    const float* __restrict__ Wk, const float* __restrict__ bk,
    const float* __restrict__ Wv, const float* __restrict__ bv,
    const float* __restrict__ arel, const float* __restrict__ mrel,
    const float* __restrict__ Wa,
    short* __restrict__ WThi, short* __restrict__ WaThi,
    float* __restrict__ bias, int F)
{
    __shared__ float Trow[64];
    int c = blockIdx.y;
    int f = blockIdx.x * 256 + threadIdx.x;

    if (c >= 640) {                       // fused Wa transpose
        int cc = c - 640;                 // 0..127
        if (blockIdx.x == 0 && threadIdx.x < 128) {
            int ff = threadIdx.x;
            WaThi[cc * 128 + ff] = cvt_rn(Wa[(long)ff * 128 + cc]);
        }
        return;
    }

    float w = 0.f, b = 0.f;
    if (c < 128) {
        if (f < F) w = Wq[(long)f * 128 + c];
        b = bq[c];
    } else {
        int cc = c - 128;              // 0..511
        int r  = cc >> 8;              // relation
        int hb = cc & 255;             // within relation
        int h  = hb >> 7;              // head
        int kv = (hb >> 6) & 1;        // 0 = k, 1 = v
        int e  = hb & 63;              // element within head
        const float* Wsrc = kv ? Wv : Wk;
        const float* bsrc = kv ? bv : bk;
        const float* T    = kv ? mrel : arel;
        const float* Tr = T + (long)(r * 2 + h) * 4096 + e;
        if (threadIdx.x < 64) Trow[threadIdx.x] = Tr[(long)threadIdx.x * 64];
        __syncthreads();
        if (f < F) {
            const float* Wrow = Wsrc + (long)f * 128 + h * 64;
            float s = 0.f;
            #pragma unroll 4
            for (int d = 0; d < 64; ++d) s = fmaf(Wrow[d], Trow[d], s);
            w = s;
        }
        if (f == 0) {
            const float* brow = bsrc + h * 64;
            float sb = 0.f;
            for (int d = 0; d < 64; ++d) sb = fmaf(brow[d], Trow[d], sb);
            b = sb;
        }
    }
    if (f < F) WThi[(long)c * F + f] = cvt_rn(w);
    if (f == 0) bias[c] = b;
}

// ============ CSR build (3-pass parallel scan, R14) ============
__global__ void csr_count2(const int* __restrict__ e0p, const int* __restrict__ e1p,
                           int* __restrict__ counts, int E, int N)
{
    int e = blockIdx.x * 256 + threadIdx.x;
    int r = blockIdx.y;
    const int* dst = (r ? e1p : e0p) + E;
    if (e < E) atomicAdd(&counts[r * N + dst[e]], 1);
}

__global__ __launch_bounds__(256) void scan_blksum(
    const int* __restrict__ counts, int* __restrict__ blksum, int N, int nb)
{
    int r = blockIdx.y, b = blockIdx.x, t = threadIdx.x;
    int i = b * 256 + t;
    __shared__ int sh[256];
    sh[t] = (i < N) ? counts[(long)r * N + i] : 0;
    __syncthreads();
    #pragma unroll
    for (int o = 128; o > 0; o >>= 1) {
        if (t < o) sh[t] += sh[t + o];
        __syncthreads();
    }
    if (t == 0) blksum[r * nb + b] = sh[0];
}

__global__ __launch_bounds__(1024) void scan_blkoff(
    int* __restrict__ blksum, int nb)
{
    int r = blockIdx.x, t = threadIdx.x;
    __shared__ int sh[1024];
    int v = (t < nb) ? blksum[r * nb + t] : 0;
    sh[t] = v;
    __syncthreads();
    for (int o = 1; o < 1024; o <<= 1) {
        int u = (t >= o) ? sh[t - o] : 0;
        __syncthreads();
        sh[t] += u;
        __syncthreads();
    }
    if (t < nb) blksum[r * nb + t] = sh[t] - v;   // exclusive offset
}

__global__ __launch_bounds__(256) void scan_final(
    const int* __restrict__ counts, const int* __restrict__ blksum,
    int* __restrict__ off0, int* __restrict__ off1,
    int* __restrict__ cursor, int N, int nb, int E)
{
    int r = blockIdx.y, b = blockIdx.x, t = threadIdx.x;
    int i = b * 256 + t;
    int* offs = r ? off1 : off0;
    __shared__ int sh[256];
    int v = (i < N) ? counts[(long)r * N + i] : 0;
    sh[t] = v;
    __syncthreads();
    for (int o = 1; o < 256; o <<= 1) {
        int u = (t >= o) ? sh[t - o] : 0;
        __syncthreads();
        sh[t] += u;
        __syncthreads();
    }
    int excl = sh[t] - v + blksum[r * nb + b];
    if (i < N) { offs[i] = excl; cursor[(long)r * N + i] = excl; }
    if (i == 0 && b == 0) offs[N] = E;
}

__global__ void csr_fill2(const int* __restrict__ e0p, const int* __restrict__ e1p,
                          int* __restrict__ cursor,
                          int* __restrict__ ss0, int* __restrict__ ss1, int E, int N)
{
    int e = blockIdx.x * 256 + threadIdx.x;
    if (e >= E) return;
    int r = blockIdx.y;
    const int* ed = r ? e1p : e0p;
    int* ss = r ? ss1 : ss0;
    int pos = atomicAdd(&cursor[r * N + ed[E + e]], 1);
    ss[pos] = ed[e];
}

// ============ node attention: one wave per node, both heads (R9 form) ============
__global__ __launch_bounds__(256) void node_attn_kernel(
    const _Float16* __restrict__ qh,       // [N][128] fp16
    const _Float16* __restrict__ kvh,      // [N][512] fp16
    const int* __restrict__ off0, const int* __restrict__ ss0,
    const int* __restrict__ off1, const int* __restrict__ ss1,
    const float* __restrict__ prel,        // [2][2] (r,h)
    short* __restrict__ ohi, int N)
{
    int d = blockIdx.x * 4 + (threadIdx.x >> 6);
    if (d >= N) return;
    int lane = threadIdx.x & 63;
    int g = lane >> 5, h = (lane >> 4) & 1, l = lane & 15;

    halfx4 qv = *(const halfx4*)(qh + (long)d * 128 + h * 64 + l * 4);
    float4 q4;
    q4.x = (float)qv[0]; q4.y = (float)qv[1];
    q4.z = (float)qv[2]; q4.w = (float)qv[3];

    int c0 = off0[d], b0 = off0[d + 1];
    int c1 = off1[d], b1 = off1[d + 1];
    const _Float16* kp0 = kvh + h * 128 + l * 4;
    const _Float16* vp0 = kp0 + 64;
    const _Float16* kp1 = kp0 + 256;
    const _Float16* vp1 = vp0 + 256;
    float pr0 = prel[h] * 0.125f;       // includes 1/sqrt(64)
    float pr1 = prel[2 + h] * 0.125f;

    const float4 fz = {0.f, 0.f, 0.f, 0.f};
    float4 num0 = fz, num1 = fz;
    float den0 = 0.f, den1 = 0.f;

    while (c0 < b0 || c1 < b1) {
        float4 k0 = fz, v0 = fz, k1 = fz, v1 = fz;
        bool a0 = (c0 < b0) && (c0 + g < b0);
        bool a1 = (c1 < b1) && (c1 + g < b1);
        if (a0) {
            long so = (long)ss0[c0 + g] * 512;
            halfx4 kh = *(const halfx4*)(kp0 + so);
            halfx4 vh = *(const halfx4*)(vp0 + so);
            k0.x = (float)kh[0]; k0.y = (float)kh[1];
            k0.z = (float)kh[2]; k0.w = (float)kh[3];
            v0.x = (float)vh[0]; v0.y = (float)vh[1];
            v0.z = (float)vh[2]; v0.w = (float)vh[3];
        }
        if (a1) {
            long so = (long)ss1[c1 + g] * 512;
            halfx4 kh = *(const halfx4*)(kp1 + so);
            halfx4 vh = *(const halfx4*)(vp1 + so);
            k1.x = (float)kh[0]; k1.y = (float)kh[1];
            k1.z = (float)kh[2]; k1.w = (float)kh[3];
            v1.x = (float)vh[0]; v1.y = (float)vh[1];
            v1.z = (float)vh[2]; v1.w = (float)vh[3];
        }
        if (c0 < b0) {
            float p = q4.x*k0.x + q4.y*k0.y + q4.z*k0.z + q4.w*k0.w;
            p += __shfl_xor(p, 1, 16);
            p += __shfl_xor(p, 2, 16);
            p += __shfl_xor(p, 4, 16);
            p += __shfl_xor(p, 8, 16);
            float w = a0 ? __expf(p * pr0) : 0.f;
            den0 += w;
            num0.x = fmaf(w, v0.x, num0.x);
            num0.y = fmaf(w, v0.y, num0.y);
            num0.z = fmaf(w, v0.z, num0.z);
            num0.w = fmaf(w, v0.w, num0.w);
            c0 += 2;
        }
        if (c1 < b1) {
            float p = q4.x*k1.x + q4.y*k1.y + q4.z*k1.z + q4.w*k1.w;
            p += __shfl_xor(p, 1, 16);
            p += __shfl_xor(p, 2, 16);
            p += __shfl_xor(p, 4, 16);
            p += __shfl_xor(p, 8, 16);
            float w = a1 ? __expf(p * pr1) : 0.f;
            den1 += w;
            num1.x = fmaf(w, v1.x, num1.x);
            num1.y = fmaf(w, v1.y, num1.y);
            num1.z = fmaf(w, v1.z, num1.z);
            num1.w = fmaf(w, v1.w, num1.w);
            c1 += 2;
        }
    }

    den0 += __shfl_xor(den0, 32, 64);
    den1 += __shfl_xor(den1, 32, 64);
    float inv0 = 1.f / (den0 + 1e-16f);
    float inv1 = 1.f / (den1 + 1e-16f);
    float4 accv;
    accv.x = num0.x * inv0 + num1.x * inv1;
    accv.y = num0.y * inv0 + num1.y * inv1;
    accv.z = num0.z * inv0 + num1.z * inv1;
    accv.w = num0.w * inv0 + num1.w * inv1;
    accv.x += __shfl_xor(accv.x, 32, 64);
    accv.y += __shfl_xor(accv.y, 32, 64);
    accv.z += __shfl_xor(accv.z, 32, 64);
    accv.w += __shfl_xor(accv.w, 32, 64);

    if (g == 0) {   // 32 lanes: both heads' outputs
        const float is2 = 0.70710678118654752f;
        float o0 = 0.5f * accv.x * (1.f + erff(accv.x * is2));
        float o1 = 0.5f * accv.y * (1.f + erff(accv.y * is2));
        float o2 = 0.5f * accv.z * (1.f + erff(accv.z * is2));
        float o3 = 0.5f * accv.w * (1.f + erff(accv.w * is2));
        long oo = (long)d * 128 + h * 64 + l * 4;
        *(shortx4*)(ohi + oo) = (shortx4){cvt_rn(o0), cvt_rn(o1), cvt_rn(o2), cvt_rn(o3)};
    }
}

// ============ f32 vector GEMM kept for tiny MLP ============
#define BM 64
#define BN 64
#define BK 16
__global__ __launch_bounds__(256) void gemm_bias_kernel(
    const float* __restrict__ A, int lda,
    const float* __restrict__ B, int ldb,
    const float* __restrict__ bias,
    float* __restrict__ C, int ldc,
    int M, int K, int epilogue)
{
    __shared__ float As[BK][BM + 4];
    __shared__ float Bs[BK][BN + 4];
    const int t = threadIdx.x;
    const int row0 = blockIdx.y * BM;
    const int col0 = blockIdx.x * BN;
    const int tm = (t >> 4) << 2;
    const int tn = (t & 15) << 2;
    float acc[4][4] = {};
    for (int k0 = 0; k0 < K; k0 += BK) {
        #pragma unroll
        for (int i = 0; i < 4; ++i) {
            int idx = t + i * 256;
            int m = idx >> 4, kk = idx & 15;
            int gm = row0 + m;
            As[kk][m] = (gm < M) ? A[(long)gm * lda + (k0 + kk)] : 0.f;
        }
        #pragma unroll
        for (int i = 0; i < 4; ++i) {
            int idx = t + i * 256;
            int kk = idx >> 6, n = idx & 63;
            Bs[kk][n] = B[(long)(k0 + kk) * ldb + (col0 + n)];
        }
        __syncthreads();
        #pragma unroll
        for (int kk = 0; kk < BK; ++kk) {
            float a[4], b[4];
            #pragma unroll
            for (int i = 0; i < 4; ++i) a[i] = As[kk][tm + i];
            #pragma unroll
            for (int j = 0; j < 4; ++j) b[j] = Bs[kk][tn + j];
            #pragma unroll
            for (int i = 0; i < 4; ++i)
                #pragma unroll
                for (int j = 0; j < 4; ++j)
                    acc[i][j] = fmaf(a[i], b[j], acc[i][j]);
        }
        __syncthreads();
    }
    #pragma unroll
    for (int i = 0; i < 4; ++i) {
        int gm = row0 + tm + i;
        if (gm >= M) continue;
        #pragma unroll
        for (int j = 0; j < 4; ++j) {
            int gn = col0 + tn + j;
            float v = acc[i][j];
            if (bias) v += bias[gn];
            if (epilogue >= 1) v = fmaxf(v, 0.f);
            C[(long)gm * ldc + gn] = v;
        }
    }
}

// ============ pooling (reads bf16 hi plane) ============
__device__ inline int lower_bound_i(const int* __restrict__ a, int n, int v)
{
    int lo = 0, hi = n;
    while (lo < hi) { int mid = (lo + hi) >> 1; if (a[mid] < v) lo = mid + 1; else hi = mid; }
    return lo;
}

__global__ void pool_kernel(const short* __restrict__ hhi,
                            const int* __restrict__ batch,
                            float* __restrict__ s, int N)
{
    int g = blockIdx.x, part = blockIdx.y, c = threadIdx.x;
    int start = lower_bound_i(batch, N, g);
    int end = lower_bound_i(batch, N, g + 1);
    int cnt = end - start, parts = gridDim.y;
    int chunk = (cnt + parts - 1) / parts;
    int a = start + part * chunk;
    int b = a + chunk; if (b > end) b = end;
    if (a >= b) return;
    float sum = 0.f;
    for (int n = a; n < b; ++n)
        sum += b2f(hhi[(long)n * HDIM + c]);
    atomicAdd(&s[g * HDIM + c], sum);
}

__global__ void pool_finalize(const float* __restrict__ s, const int* __restrict__ batch,
                              float* __restrict__ g_out, int N)
{
    int g = blockIdx.x, c = threadIdx.x;
    int start = lower_bound_i(batch, N, g);
    int end = lower_bound_i(batch, N, g + 1);
    float cnt = (float)((end - start) > 1 ? (end - start) : 1);
    g_out[g * HDIM + c] = s[g * HDIM + c] / cnt;
}

// ============ host ============
extern "C" void kernel_launch(void* const* d_in, const int* in_sizes, int n_in,
                              void* d_out, int out_size, void* d_ws, size_t ws_size,
                              hipStream_t stream)
{
    const float* x      = (const float*)d_in[0];
    const int*   e0     = (const int*)d_in[1];
    const int*   e1     = (const int*)d_in[2];
    const int*   batch  = (const int*)d_in[3];
    const float* W_k1   = (const float*)d_in[4];
    const float* W_q1   = (const float*)d_in[5];
    const float* W_v1   = (const float*)d_in[6];
    const float* a_rel1 = (const float*)d_in[7];
    const float* m_rel1 = (const float*)d_in[8];
    const float* W_a1   = (const float*)d_in[9];
    const float* W_k23  = (const float*)d_in[10];
    const float* W_q23  = (const float*)d_in[11];
    const float* W_v23  = (const float*)d_in[12];
    const float* a_rel23= (const float*)d_in[13];
    const float* m_rel23= (const float*)d_in[14];
    const float* W_a23  = (const float*)d_in[15];
    const float* W_m1   = (const float*)d_in[16];
    const float* W_m2   = (const float*)d_in[17];
    const float* b_k1   = (const float*)d_in[18];
    const float* b_q1   = (const float*)d_in[19];
    const float* b_v1   = (const float*)d_in[20];
    const float* b_a1   = (const float*)d_in[21];
    const float* b_k23  = (const float*)d_in[22];
    const float* b_q23  = (const float*)d_in[23];
    const float* b_v23  = (const float*)d_in[24];
    const float* b_a23  = (const float*)d_in[25];
    const float* skip23 = (const float*)d_in[26];
    const float* b_m1   = (const float*)d_in[27];
    const float* b_m2   = (const float*)d_in[28];
    const float* p_rel1 = (const float*)d_in[29];
    const float* p_rel23= (const float*)d_in[30];

    const int N = N_NODES_C;
    const int E = in_sizes[1] / 2;
    const int F = in_sizes[0] / N;            // 512
    const long NP = (long)N * HDIM;           // 6.4M plane elements

    // ---- workspace layout ----
    float* ws    = (float*)d_ws;
    _Float16* Qh  = (_Float16*)ws;                      // N*128 fp16 (12.8 MB)
    _Float16* KVh = (_Float16*)(ws + (long)N * 128);    // N*512 fp16 (51.2 MB)
    short* ACChi = (short*)(KVh + (long)N * 512);       // plane slots
    short* ACClo = ACChi + NP;                          // unused (kept layout)
    short* H1hi  = ACClo + NP;
    short* H1lo  = H1hi + NP;                           // unused
    short* H2hi  = H1lo + NP;
    short* H2lo  = H2hi + NP;                           // unused
    short* WThi  = H2lo + NP;                           // 640*512 max
    short* WTlo  = WThi + 640 * 512;                    // unused
    short* WaThi = WTlo + 640 * 512;                    // 128*128
    short* WaTlo = WaThi + 128 * 128;                   // unused
    float* B640  = (float*)(WaTlo + 128 * 128);         // 640
    float* S     = B640 + 640;
    float* GM    = S + N_GRAPHS_C * HDIM;
    float* M1    = GM + N_GRAPHS_C * HDIM;
    int*   off0  = (int*)(M1 + N_GRAPHS_C * HDIM);      // N+1
    int*   ss0   = off0 + (N + 1);                      // E
    int*   off1  = ss0 + E;                             // N+1
    int*   ss1   = off1 + (N + 1);                      // E
    short* Xbf   = (short*)(((uintptr_t)(ss1 + E) + 15) & ~(uintptr_t)15);  // N*F bf16
    int*   counts = (int*)ws;                           // 2N ints, alias (dead before Qh written)
    int*   cursor = counts + 2 * N;                     // 2N
    int*   blksum = cursor + 2 * N;                     // 2*nb ints (alias)
    size_t needed = (size_t)((char*)(Xbf + (long)N * F) - (char*)d_ws);
    if (ws_size < needed) return;

    const int nb = (N + 255) / 256;   // 196 scan blocks per relation

    // ---- build CSR once (3-pass parallel scan); pre-convert x ----
    {
        int eb = (E + 255) / 256;
        hipMemsetAsync(counts, 0, (size_t)(2 * N) * sizeof(int), stream);
        dim3 cg(eb, 2);
        csr_count2<<<cg, 256, 0, stream>>>(e0, e1, counts, E, N);
        dim3 sg(nb, 2);
        scan_blksum<<<sg, 256, 0, stream>>>(counts, blksum, N, nb);
        scan_blkoff<<<2, 1024, 0, stream>>>(blksum, nb);
        scan_final<<<sg, 256, 0, stream>>>(counts, blksum, off0, off1, cursor, N, nb, E);
        csr_fill2<<<cg, 256, 0, stream>>>(e0, e1, cursor, ss0, ss1, E, N);
        xcvt_kernel<<<2048, 256, 0, stream>>>(x, Xbf, ((long)N * F) / 4);
    }

    const int nrb   = (N + GBM - 1) / GBM;   // 391 row blocks (TM=128)
    const int nrb64 = (N + 63) / 64;         // 782 row blocks (TM=64)

    auto run_layer = [&](const short* Ain, int DBsel, int Fin,
                         const float* Wk, const float* bk,
                         const float* Wq, const float* bq,
                         const float* Wv, const float* bv,
                         const float* arel, const float* mrel, const float* prel,
                         const float* Wa, const float* ba,
                         const float* gate, const short* skipHi,
                         short* outHi) {
        dim3 bg((Fin + 255) / 256, 768);   // [640,768) = fused WaT transpose
        build_wbigT_p<<<bg, 256, 0, stream>>>(Wq, bq, Wk, bk, Wv, bv,
                                              arel, mrel, Wa,
                                              WThi, WaThi, B640, Fin);
        if (DBsel) {
            // layer-1 QKV (K=512): TM=128 dbuf — R14-measured best (84 us)
            int qb = (640 / GBN) * nrb;
            gemm_planes<1, 128><<<qb, 256, 0, stream>>>(Ain, Fin, WThi, Fin,
                B640, Qh, (short*)KVh, N, 640, Fin, 0, nullptr, nullptr);
        } else {
            // QKV 2/3 (K=128): ONESHOT TM=64 — 1 barrier per block
            int qb = (640 / GBN) * nrb64;
            gemm_planes<2, 64><<<qb, 256, 0, stream>>>(Ain, Fin, WThi, Fin,
                B640, Qh, (short*)KVh, N, 640, Fin, 0, nullptr, nullptr);
        }

        node_attn_kernel<<<(N + 3) / 4, 256, 0, stream>>>(
            Qh, KVh, off0, ss0, off1, ss1, prel, ACChi, N);

        // out-GEMM (K=128): ONESHOT TM=64 — 1 barrier per block
        gemm_planes<2, 64><<<nrb64, 256, 0, stream>>>(ACChi, 128, WaThi, 128,
            ba, nullptr, outHi, N, 128, 128,
            gate ? 3 : 2, gate, skipHi);
    };

    // layer 1 (bf16 x, K=512 -> dbuf TM=128) -> H1 plane
    run_layer(Xbf, 1, F, W_k1, b_k1, W_q1, b_q1, W_v1, b_v1,
              a_rel1, m_rel1, p_rel1, W_a1, b_a1,
              nullptr, nullptr, H1hi);
    // layer 2 (H1 plane, K=128 -> ONESHOT, gated skip from H1) -> H2
    run_layer(H1hi, 0, HDIM, W_k23, b_k23, W_q23, b_q23, W_v23, b_v23,
              a_rel23, m_rel23, p_rel23, W_a23, b_a23,
              skip23, H1hi, H2hi);
    // layer 3 (H2 plane, gated skip from H2) -> H1 plane (reuse)
    run_layer(H2hi, 0, HDIM, W_k23 + 16384, b_k23 + 128, W_q23 + 16384, b_q23 + 128,
              W_v23 + 16384, b_v23 + 128, a_rel23 + 16384, m_rel23 + 16384,
              p_rel23 + 4, W_a23 + 16384, b_a23 + 128,
              skip23 + 1, H2hi, H1hi);

    // global mean pool (batch sorted)
    hipMemsetAsync(S, 0, (size_t)N_GRAPHS_C * HDIM * sizeof(float), stream);
    dim3 pg(N_GRAPHS_C, 8);
    pool_kernel<<<pg, HDIM, 0, stream>>>(H1hi, batch, S, N);
    pool_finalize<<<N_GRAPHS_C, HDIM, 0, stream>>>(S, batch, GM, N);

    // MLP
    {
        dim3 g1(128 / BN, 1);
        gemm_bias_kernel<<<g1, 256, 0, stream>>>(GM, 128, W_m1, 128, b_m1, M1, 128,
                                                 N_GRAPHS_C, 128, 1);
        dim3 g2(256 / BN, 1);
        gemm_bias_kernel<<<g2, 256, 0, stream>>>(M1, 128, W_m2, 256, b_m2,
                                                 (float*)d_out, 256, N_GRAPHS_C, 128, 0);
    }
}

// Round 17
// 709.652 us; speedup vs baseline: 1.0583x; 1.0583x over previous
//
#include <hip/hip_runtime.h>
#include <math.h>
#include <stdint.h>

#define N_NODES_C 50000
#define N_GRAPHS_C 64
#define HDIM 128

typedef short bf16x8 __attribute__((ext_vector_type(8)));
typedef short shortx4 __attribute__((ext_vector_type(4)));
typedef float floatx4 __attribute__((ext_vector_type(4)));
typedef _Float16 halfx4 __attribute__((ext_vector_type(4)));

// f32 -> bf16 round-to-nearest-even
__device__ __forceinline__ short cvt_rn(float x) {
    union { float f; unsigned u; } a; a.f = x;
    unsigned r = a.u + 0x7FFFu + ((a.u >> 16) & 1u);
    return (short)(r >> 16);
}

__device__ __forceinline__ float b2f(short s) {
    union { unsigned u; float f; } x; x.u = ((unsigned)(unsigned short)s) << 16;
    return x.f;
}

// async global->LDS copy, 16 B per lane, LDS dest = wave-uniform base + lane*16
__device__ __forceinline__ void gld_lds16(const void* gsrc, void* ldst) {
    __builtin_amdgcn_global_load_lds(
        (const __attribute__((address_space(1))) unsigned int*)gsrc,
        (__attribute__((address_space(3))) unsigned int*)ldst,
        16, 0, 0);
}

// ============ x f32 -> bf16 pre-convert (R13) ============
__global__ __launch_bounds__(256) void xcvt_kernel(
    const float* __restrict__ x, short* __restrict__ xb, long nq)
{
    long i = (long)blockIdx.x * 256 + threadIdx.x;
    long stride = (long)gridDim.x * 256;
    for (; i < nq; i += stride) {
        float4 f = *(const float4*)(x + i * 4);
        *(shortx4*)(xb + i * 4) =
            (shortx4){cvt_rn(f.x), cvt_rn(f.y), cvt_rn(f.z), cvt_rn(f.w)};
    }
}

// ============ MFMA GEMM, single bf16 plane ============
// R17: every instantiation at its best-MEASURED config (17-round ledger):
//   <1,128> layer-1 QKV (K=512): dbuf 2-phase, 32 KB LDS, (256,3) — 83 us (R16)
//   <0,128> QKV 2/3 (K=128): single-buffer, 16 KB LDS, (256,3) — R14/R15
//   <0,64>  out-GEMM (K=128): single-buffer, 12 KB LDS, (256,4) — R11..R15
// ONESHOT (R16) reverted: NB=4 needed 48 KB LDS -> occupancy capped below
// its launch bound and 12-deep load bursts serialized on the LDS write port.
// bf16 granule XOR-swizzle both sides; XCD-bijective block swizzle (frozen).
// mode 0: cols [0,128) -> fp16 Q (ld 128); cols [128,640) -> fp16 KV (ld 512)
// mode 2: Chi = bf16 relu(v + bias)            (ldc = 128)
// mode 3: Chi = bf16 relu(gate*v+bias + (1-gate)*prev_hi)
#define GBM 128
#define GBN 128
#define GBK 32

template<int DB, int TM>
__global__ __launch_bounds__(256, TM == 64 ? 4 : 3) void gemm_planes(
    const short* __restrict__ Ahi, int lda,
    const short* __restrict__ Bhi, int ldbt,
    const float* __restrict__ bias,
    _Float16* __restrict__ Qh, short* __restrict__ Chi,
    int M, int Ntot, int K,
    int mode, const float* __restrict__ skipGate,
    const short* __restrict__ Phi)
{
    constexpr int ASZ = TM * GBK;                              // shorts / buffer
    constexpr int BSZ = GBN * GBK;
    constexpr int NB  = DB ? 2 : 1;                            // LDS buffers
    constexpr int NI  = TM / 32;                               // A fragments/wave
    constexpr int WR  = TM / 2;                                // rows per wm group
    __shared__ __align__(16) short AsH[NB * ASZ];
    __shared__ __align__(16) short BsH[NB * BSZ];

    const int t = threadIdx.x;
    const int lane = t & 63;
    const int wave = t >> 6;
    const int wm = wave & 1, wn = wave >> 1;
    const int quad = lane >> 4, l15 = lane & 15;

    // XCD-bijective chunked swizzle (valid for any nwg), column-fastest decode
    const int nwg = gridDim.x, bid0 = blockIdx.x;
    const int qq = nwg >> 3, rr = nwg & 7;
    const int xcd = bid0 & 7, idx = bid0 >> 3;
    const int swz = (xcd < rr ? xcd * (qq + 1)
                              : rr * (qq + 1) + (xcd - rr) * qq) + idx;
    const int ncb = (Ntot + GBN - 1) / GBN;
    const long row0 = (long)(swz / ncb) * TM;
    const long col0 = (long)(swz % ncb) * GBN;

    floatx4 acc[NI][4];
    #pragma unroll
    for (int i = 0; i < NI; ++i)
        #pragma unroll
        for (int j = 0; j < 4; ++j)
            acc[i][j] = (floatx4){0.f, 0.f, 0.f, 0.f};

    const int nkt = K / GBK;

    auto stage = [&](int buf, int k0) {
        int r16 = lane >> 2, g4 = lane & 3;
        int gs = (g4 ^ ((r16 >> 1) & 3)) * 8;       // granule swizzle (src side)
        #pragma unroll
        for (int cc = 0; cc < TM / 64; ++cc) {      // 2 chunks (TM=128) / 1 (TM=64)
            int ch = wave * (TM / 64) + cc;
            long gr = row0 + ch * 16 + r16;
            if (gr > M - 1) gr = M - 1;
            gld_lds16(Ahi + gr * lda + k0 + gs, AsH + buf * ASZ + ch * 512);
        }
        #pragma unroll
        for (int cc = 0; cc < 2; ++cc) {
            int ch = wave * 2 + cc;
            long gc = col0 + ch * 16 + r16;
            if (gc > Ntot - 1) gc = Ntot - 1;
            gld_lds16(Bhi + gc * ldbt + k0 + gs, BsH + buf * BSZ + ch * 512);
        }
    };

    auto compute = [&](int buf) {
        bf16x8 aH[NI], bH[4];
        #pragma unroll
        for (int i = 0; i < NI; ++i) {
            int row = wm * WR + i * 16 + l15;
            int off = buf * ASZ + row * 32 + ((quad ^ ((row >> 1) & 3)) * 8);
            aH[i] = *(const bf16x8*)&AsH[off];
        }
        #pragma unroll
        for (int j = 0; j < 4; ++j) {
            int row = wn * 64 + j * 16 + l15;
            int off = buf * BSZ + row * 32 + ((quad ^ ((row >> 1) & 3)) * 8);
            bH[j] = *(const bf16x8*)&BsH[off];
        }
        #pragma unroll
        for (int i = 0; i < NI; ++i)
            #pragma unroll
            for (int j = 0; j < 4; ++j)
                acc[i][j] = __builtin_amdgcn_mfma_f32_16x16x32_bf16(aH[i], bH[j], acc[i][j], 0, 0, 0);
    };

    if constexpr (DB) {
        stage(0, 0);
        int cur = 0;
        for (int kt = 0; kt < nkt; ++kt) {
            __syncthreads();   // own stage landed; all waves done with cur^1
            if (kt + 1 < nkt) stage(cur ^ 1, (kt + 1) * GBK);
            compute(cur);
            cur ^= 1;
        }
    } else {
        for (int kt = 0; kt < nkt; ++kt) {
            stage(0, kt * GBK);
            __syncthreads();
            compute(0);
            __syncthreads();
        }
    }

    float gate = 0.f;
    if (mode == 3) gate = 1.f / (1.f + __expf(-skipGate[0]));
    _Float16* kvout = (_Float16*)Chi;   // mode 0 fp16 KV destination

    #pragma unroll
    for (int i = 0; i < NI; ++i) {
        #pragma unroll
        for (int r4 = 0; r4 < 4; ++r4) {
            long grow = row0 + wm * WR + i * 16 + quad * 4 + r4;
            if (grow >= M) continue;
            #pragma unroll
            for (int j = 0; j < 4; ++j) {
                long gcol = col0 + wn * 64 + j * 16 + l15;
                if (gcol >= Ntot) continue;
                float v = acc[i][j][r4];
                if (bias) v += bias[gcol];
                if (mode == 0) {
                    if (gcol < 128) Qh[grow * 128 + gcol] = (_Float16)v;
                    else kvout[grow * 512 + (gcol - 128)] = (_Float16)v;
                } else {
                    if (mode == 3) {
                        float pv = b2f(Phi[grow * 128 + gcol]);
                        v = gate * v + (1.f - gate) * pv;
                    }
                    v = fmaxf(v, 0.f);
                    Chi[grow * 128 + gcol] = cvt_rn(v);
                }
            }
        }
    }
}

// ============ build fused WbigT[640, F] bf16 plane + bias640 + WaT ============
__global__ __launch_bounds__(256) void build_wbigT_p(
    const float* __restrict__ Wq, const float* __restrict__ bq,
    const float* __restrict__ Wk, const float* __restrict__ bk,
    const float* __restrict__ Wv, const float* __restrict__ bv,
    const float* __restrict__ arel, const float* __restrict__ mrel,
    const float* __restrict__ Wa,
    short* __restrict__ WThi, short* __restrict__ WaThi,
    float* __restrict__ bias, int F)
{
    __shared__ float Trow[64];
    int c = blockIdx.y;
    int f = blockIdx.x * 256 + threadIdx.x;

    if (c >= 640) {                       // fused Wa transpose
        int cc = c - 640;                 // 0..127
        if (blockIdx.x == 0 && threadIdx.x < 128) {
            int ff = threadIdx.x;
            WaThi[cc * 128 + ff] = cvt_rn(Wa[(long)ff * 128 + cc]);
        }
        return;
    }

    float w = 0.f, b = 0.f;
    if (c < 128) {
        if (f < F) w = Wq[(long)f * 128 + c];
        b = bq[c];
    } else {
        int cc = c - 128;              // 0..511
        int r  = cc >> 8;              // relation
        int hb = cc & 255;             // within relation
        int h  = hb >> 7;              // head
        int kv = (hb >> 6) & 1;        // 0 = k, 1 = v
        int e  = hb & 63;              // element within head
        const float* Wsrc = kv ? Wv : Wk;
        const float* bsrc = kv ? bv : bk;
        const float* T    = kv ? mrel : arel;
        const float* Tr = T + (long)(r * 2 + h) * 4096 + e;
        if (threadIdx.x < 64) Trow[threadIdx.x] = Tr[(long)threadIdx.x * 64];
        __syncthreads();
        if (f < F) {
            const float* Wrow = Wsrc + (long)f * 128 + h * 64;
            float s = 0.f;
            #pragma unroll 4
            for (int d = 0; d < 64; ++d) s = fmaf(Wrow[d], Trow[d], s);
            w = s;
        }
        if (f == 0) {
            const float* brow = bsrc + h * 64;
            float sb = 0.f;
            for (int d = 0; d < 64; ++d) sb = fmaf(brow[d], Trow[d], sb);
            b = sb;
        }
    }
    if (f < F) WThi[(long)c * F + f] = cvt_rn(w);
    if (f == 0) bias[c] = b;
}

// ============ CSR build (3-pass parallel scan, R14) ============
__global__ void csr_count2(const int* __restrict__ e0p, const int* __restrict__ e1p,
                           int* __restrict__ counts, int E, int N)
{
    int e = blockIdx.x * 256 + threadIdx.x;
    int r = blockIdx.y;
    const int* dst = (r ? e1p : e0p) + E;
    if (e < E) atomicAdd(&counts[r * N + dst[e]], 1);
}

__global__ __launch_bounds__(256) void scan_blksum(
    const int* __restrict__ counts, int* __restrict__ blksum, int N, int nb)
{
    int r = blockIdx.y, b = blockIdx.x, t = threadIdx.x;
    int i = b * 256 + t;
    __shared__ int sh[256];
    sh[t] = (i < N) ? counts[(long)r * N + i] : 0;
    __syncthreads();
    #pragma unroll
    for (int o = 128; o > 0; o >>= 1) {
        if (t < o) sh[t] += sh[t + o];
        __syncthreads();
    }
    if (t == 0) blksum[r * nb + b] = sh[0];
}

__global__ __launch_bounds__(1024) void scan_blkoff(
    int* __restrict__ blksum, int nb)
{
    int r = blockIdx.x, t = threadIdx.x;
    __shared__ int sh[1024];
    int v = (t < nb) ? blksum[r * nb + t] : 0;
    sh[t] = v;
    __syncthreads();
    for (int o = 1; o < 1024; o <<= 1) {
        int u = (t >= o) ? sh[t - o] : 0;
        __syncthreads();
        sh[t] += u;
        __syncthreads();
    }
    if (t < nb) blksum[r * nb + t] = sh[t] - v;   // exclusive offset
}

__global__ __launch_bounds__(256) void scan_final(
    const int* __restrict__ counts, const int* __restrict__ blksum,
    int* __restrict__ off0, int* __restrict__ off1,
    int* __restrict__ cursor, int N, int nb, int E)
{
    int r = blockIdx.y, b = blockIdx.x, t = threadIdx.x;
    int i = b * 256 + t;
    int* offs = r ? off1 : off0;
    __shared__ int sh[256];
    int v = (i < N) ? counts[(long)r * N + i] : 0;
    sh[t] = v;
    __syncthreads();
    for (int o = 1; o < 256; o <<= 1) {
        int u = (t >= o) ? sh[t - o] : 0;
        __syncthreads();
        sh[t] += u;
        __syncthreads();
    }
    int excl = sh[t] - v + blksum[r * nb + b];
    if (i < N) { offs[i] = excl; cursor[(long)r * N + i] = excl; }
    if (i == 0 && b == 0) offs[N] = E;
}

__global__ void csr_fill2(const int* __restrict__ e0p, const int* __restrict__ e1p,
                          int* __restrict__ cursor,
                          int* __restrict__ ss0, int* __restrict__ ss1, int E, int N)
{
    int e = blockIdx.x * 256 + threadIdx.x;
    if (e >= E) return;
    int r = blockIdx.y;
    const int* ed = r ? e1p : e0p;
    int* ss = r ? ss1 : ss0;
    int pos = atomicAdd(&cursor[r * N + ed[E + e]], 1);
    ss[pos] = ed[e];
}

// ============ node attention: one wave per node, both heads (R9 form) ============
__global__ __launch_bounds__(256) void node_attn_kernel(
    const _Float16* __restrict__ qh,       // [N][128] fp16
    const _Float16* __restrict__ kvh,      // [N][512] fp16
    const int* __restrict__ off0, const int* __restrict__ ss0,
    const int* __restrict__ off1, const int* __restrict__ ss1,
    const float* __restrict__ prel,        // [2][2] (r,h)
    short* __restrict__ ohi, int N)
{
    int d = blockIdx.x * 4 + (threadIdx.x >> 6);
    if (d >= N) return;
    int lane = threadIdx.x & 63;
    int g = lane >> 5, h = (lane >> 4) & 1, l = lane & 15;

    halfx4 qv = *(const halfx4*)(qh + (long)d * 128 + h * 64 + l * 4);
    float4 q4;
    q4.x = (float)qv[0]; q4.y = (float)qv[1];
    q4.z = (float)qv[2]; q4.w = (float)qv[3];

    int c0 = off0[d], b0 = off0[d + 1];
    int c1 = off1[d], b1 = off1[d + 1];
    const _Float16* kp0 = kvh + h * 128 + l * 4;
    const _Float16* vp0 = kp0 + 64;
    const _Float16* kp1 = kp0 + 256;
    const _Float16* vp1 = vp0 + 256;
    float pr0 = prel[h] * 0.125f;       // includes 1/sqrt(64)
    float pr1 = prel[2 + h] * 0.125f;

    const float4 fz = {0.f, 0.f, 0.f, 0.f};
    float4 num0 = fz, num1 = fz;
    float den0 = 0.f, den1 = 0.f;

    while (c0 < b0 || c1 < b1) {
        float4 k0 = fz, v0 = fz, k1 = fz, v1 = fz;
        bool a0 = (c0 < b0) && (c0 + g < b0);
        bool a1 = (c1 < b1) && (c1 + g < b1);
        if (a0) {
            long so = (long)ss0[c0 + g] * 512;
            halfx4 kh = *(const halfx4*)(kp0 + so);
            halfx4 vh = *(const halfx4*)(vp0 + so);
            k0.x = (float)kh[0]; k0.y = (float)kh[1];
            k0.z = (float)kh[2]; k0.w = (float)kh[3];
            v0.x = (float)vh[0]; v0.y = (float)vh[1];
            v0.z = (float)vh[2]; v0.w = (float)vh[3];
        }
        if (a1) {
            long so = (long)ss1[c1 + g] * 512;
            halfx4 kh = *(const halfx4*)(kp1 + so);
            halfx4 vh = *(const halfx4*)(vp1 + so);
            k1.x = (float)kh[0]; k1.y = (float)kh[1];
            k1.z = (float)kh[2]; k1.w = (float)kh[3];
            v1.x = (float)vh[0]; v1.y = (float)vh[1];
            v1.z = (float)vh[2]; v1.w = (float)vh[3];
        }
        if (c0 < b0) {
            float p = q4.x*k0.x + q4.y*k0.y + q4.z*k0.z + q4.w*k0.w;
            p += __shfl_xor(p, 1, 16);
            p += __shfl_xor(p, 2, 16);
            p += __shfl_xor(p, 4, 16);
            p += __shfl_xor(p, 8, 16);
            float w = a0 ? __expf(p * pr0) : 0.f;
            den0 += w;
            num0.x = fmaf(w, v0.x, num0.x);
            num0.y = fmaf(w, v0.y, num0.y);
            num0.z = fmaf(w, v0.z, num0.z);
            num0.w = fmaf(w, v0.w, num0.w);
            c0 += 2;
        }
        if (c1 < b1) {
            float p = q4.x*k1.x + q4.y*k1.y + q4.z*k1.z + q4.w*k1.w;
            p += __shfl_xor(p, 1, 16);
            p += __shfl_xor(p, 2, 16);
            p += __shfl_xor(p, 4, 16);
            p += __shfl_xor(p, 8, 16);
            float w = a1 ? __expf(p * pr1) : 0.f;
            den1 += w;
            num1.x = fmaf(w, v1.x, num1.x);
            num1.y = fmaf(w, v1.y, num1.y);
            num1.z = fmaf(w, v1.z, num1.z);
            num1.w = fmaf(w, v1.w, num1.w);
            c1 += 2;
        }
    }

    den0 += __shfl_xor(den0, 32, 64);
    den1 += __shfl_xor(den1, 32, 64);
    float inv0 = 1.f / (den0 + 1e-16f);
    float inv1 = 1.f / (den1 + 1e-16f);
    float4 accv;
    accv.x = num0.x * inv0 + num1.x * inv1;
    accv.y = num0.y * inv0 + num1.y * inv1;
    accv.z = num0.z * inv0 + num1.z * inv1;
    accv.w = num0.w * inv0 + num1.w * inv1;
    accv.x += __shfl_xor(accv.x, 32, 64);
    accv.y += __shfl_xor(accv.y, 32, 64);
    accv.z += __shfl_xor(accv.z, 32, 64);
    accv.w += __shfl_xor(accv.w, 32, 64);

    if (g == 0) {   // 32 lanes: both heads' outputs
        const float is2 = 0.70710678118654752f;
        float o0 = 0.5f * accv.x * (1.f + erff(accv.x * is2));
        float o1 = 0.5f * accv.y * (1.f + erff(accv.y * is2));
        float o2 = 0.5f * accv.z * (1.f + erff(accv.z * is2));
        float o3 = 0.5f * accv.w * (1.f + erff(accv.w * is2));
        long oo = (long)d * 128 + h * 64 + l * 4;
        *(shortx4*)(ohi + oo) = (shortx4){cvt_rn(o0), cvt_rn(o1), cvt_rn(o2), cvt_rn(o3)};
    }
}

// ============ f32 vector GEMM kept for tiny MLP ============
#define BM 64
#define BN 64
#define BK 16
__global__ __launch_bounds__(256) void gemm_bias_kernel(
    const float* __restrict__ A, int lda,
    const float* __restrict__ B, int ldb,
    const float* __restrict__ bias,
    float* __restrict__ C, int ldc,
    int M, int K, int epilogue)
{
    __shared__ float As[BK][BM + 4];
    __shared__ float Bs[BK][BN + 4];
    const int t = threadIdx.x;
    const int row0 = blockIdx.y * BM;
    const int col0 = blockIdx.x * BN;
    const int tm = (t >> 4) << 2;
    const int tn = (t & 15) << 2;
    float acc[4][4] = {};
    for (int k0 = 0; k0 < K; k0 += BK) {
        #pragma unroll
        for (int i = 0; i < 4; ++i) {
            int idx = t + i * 256;
            int m = idx >> 4, kk = idx & 15;
            int gm = row0 + m;
            As[kk][m] = (gm < M) ? A[(long)gm * lda + (k0 + kk)] : 0.f;
        }
        #pragma unroll
        for (int i = 0; i < 4; ++i) {
            int idx = t + i * 256;
            int kk = idx >> 6, n = idx & 63;
            Bs[kk][n] = B[(long)(k0 + kk) * ldb + (col0 + n)];
        }
        __syncthreads();
        #pragma unroll
        for (int kk = 0; kk < BK; ++kk) {
            float a[4], b[4];
            #pragma unroll
            for (int i = 0; i < 4; ++i) a[i] = As[kk][tm + i];
            #pragma unroll
            for (int j = 0; j < 4; ++j) b[j] = Bs[kk][tn + j];
            #pragma unroll
            for (int i = 0; i < 4; ++i)
                #pragma unroll
                for (int j = 0; j < 4; ++j)
                    acc[i][j] = fmaf(a[i], b[j], acc[i][j]);
        }
        __syncthreads();
    }
    #pragma unroll
    for (int i = 0; i < 4; ++i) {
        int gm = row0 + tm + i;
        if (gm >= M) continue;
        #pragma unroll
        for (int j = 0; j < 4; ++j) {
            int gn = col0 + tn + j;
            float v = acc[i][j];
            if (bias) v += bias[gn];
            if (epilogue >= 1) v = fmaxf(v, 0.f);
            C[(long)gm * ldc + gn] = v;
        }
    }
}

// ============ pooling (reads bf16 hi plane) ============
__device__ inline int lower_bound_i(const int* __restrict__ a, int n, int v)
{
    int lo = 0, hi = n;
    while (lo < hi) { int mid = (lo + hi) >> 1; if (a[mid] < v) lo = mid + 1; else hi = mid; }
    return lo;
}

__global__ void pool_kernel(const short* __restrict__ hhi,
                            const int* __restrict__ batch,
                            float* __restrict__ s, int N)
{
    int g = blockIdx.x, part = blockIdx.y, c = threadIdx.x;
    int start = lower_bound_i(batch, N, g);
    int end = lower_bound_i(batch, N, g + 1);
    int cnt = end - start, parts = gridDim.y;
    int chunk = (cnt + parts - 1) / parts;
    int a = start + part * chunk;
    int b = a + chunk; if (b > end) b = end;
    if (a >= b) return;
    float sum = 0.f;
    for (int n = a; n < b; ++n)
        sum += b2f(hhi[(long)n * HDIM + c]);
    atomicAdd(&s[g * HDIM + c], sum);
}

__global__ void pool_finalize(const float* __restrict__ s, const int* __restrict__ batch,
                              float* __restrict__ g_out, int N)
{
    int g = blockIdx.x, c = threadIdx.x;
    int start = lower_bound_i(batch, N, g);
    int end = lower_bound_i(batch, N, g + 1);
    float cnt = (float)((end - start) > 1 ? (end - start) : 1);
    g_out[g * HDIM + c] = s[g * HDIM + c] / cnt;
}

// ============ host ============
extern "C" void kernel_launch(void* const* d_in, const int* in_sizes, int n_in,
                              void* d_out, int out_size, void* d_ws, size_t ws_size,
                              hipStream_t stream)
{
    const float* x      = (const float*)d_in[0];
    const int*   e0     = (const int*)d_in[1];
    const int*   e1     = (const int*)d_in[2];
    const int*   batch  = (const int*)d_in[3];
    const float* W_k1   = (const float*)d_in[4];
    const float* W_q1   = (const float*)d_in[5];
    const float* W_v1   = (const float*)d_in[6];
    const float* a_rel1 = (const float*)d_in[7];
    const float* m_rel1 = (const float*)d_in[8];
    const float* W_a1   = (const float*)d_in[9];
    const float* W_k23  = (const float*)d_in[10];
    const float* W_q23  = (const float*)d_in[11];
    const float* W_v23  = (const float*)d_in[12];
    const float* a_rel23= (const float*)d_in[13];
    const float* m_rel23= (const float*)d_in[14];
    const float* W_a23  = (const float*)d_in[15];
    const float* W_m1   = (const float*)d_in[16];
    const float* W_m2   = (const float*)d_in[17];
    const float* b_k1   = (const float*)d_in[18];
    const float* b_q1   = (const float*)d_in[19];
    const float* b_v1   = (const float*)d_in[20];
    const float* b_a1   = (const float*)d_in[21];
    const float* b_k23  = (const float*)d_in[22];
    const float* b_q23  = (const float*)d_in[23];
    const float* b_v23  = (const float*)d_in[24];
    const float* b_a23  = (const float*)d_in[25];
    const float* skip23 = (const float*)d_in[26];
    const float* b_m1   = (const float*)d_in[27];
    const float* b_m2   = (const float*)d_in[28];
    const float* p_rel1 = (const float*)d_in[29];
    const float* p_rel23= (const float*)d_in[30];

    const int N = N_NODES_C;
    const int E = in_sizes[1] / 2;
    const int F = in_sizes[0] / N;            // 512
    const long NP = (long)N * HDIM;           // 6.4M plane elements

    // ---- workspace layout ----
    float* ws    = (float*)d_ws;
    _Float16* Qh  = (_Float16*)ws;                      // N*128 fp16 (12.8 MB)
    _Float16* KVh = (_Float16*)(ws + (long)N * 128);    // N*512 fp16 (51.2 MB)
    short* ACChi = (short*)(KVh + (long)N * 512);       // plane slots
    short* ACClo = ACChi + NP;                          // unused (kept layout)
    short* H1hi  = ACClo + NP;
    short* H1lo  = H1hi + NP;                           // unused
    short* H2hi  = H1lo + NP;
    short* H2lo  = H2hi + NP;                           // unused
    short* WThi  = H2lo + NP;                           // 640*512 max
    short* WTlo  = WThi + 640 * 512;                    // unused
    short* WaThi = WTlo + 640 * 512;                    // 128*128
    short* WaTlo = WaThi + 128 * 128;                   // unused
    float* B640  = (float*)(WaTlo + 128 * 128);         // 640
    float* S     = B640 + 640;
    float* GM    = S + N_GRAPHS_C * HDIM;
    float* M1    = GM + N_GRAPHS_C * HDIM;
    int*   off0  = (int*)(M1 + N_GRAPHS_C * HDIM);      // N+1
    int*   ss0   = off0 + (N + 1);                      // E
    int*   off1  = ss0 + E;                             // N+1
    int*   ss1   = off1 + (N + 1);                      // E
    short* Xbf   = (short*)(((uintptr_t)(ss1 + E) + 15) & ~(uintptr_t)15);  // N*F bf16
    int*   counts = (int*)ws;                           // 2N ints, alias (dead before Qh written)
    int*   cursor = counts + 2 * N;                     // 2N
    int*   blksum = cursor + 2 * N;                     // 2*nb ints (alias)
    size_t needed = (size_t)((char*)(Xbf + (long)N * F) - (char*)d_ws);
    if (ws_size < needed) return;

    const int nb = (N + 255) / 256;   // 196 scan blocks per relation

    // ---- build CSR once (3-pass parallel scan); pre-convert x ----
    {
        int eb = (E + 255) / 256;
        hipMemsetAsync(counts, 0, (size_t)(2 * N) * sizeof(int), stream);
        dim3 cg(eb, 2);
        csr_count2<<<cg, 256, 0, stream>>>(e0, e1, counts, E, N);
        dim3 sg(nb, 2);
        scan_blksum<<<sg, 256, 0, stream>>>(counts, blksum, N, nb);
        scan_blkoff<<<2, 1024, 0, stream>>>(blksum, nb);
        scan_final<<<sg, 256, 0, stream>>>(counts, blksum, off0, off1, cursor, N, nb, E);
        csr_fill2<<<cg, 256, 0, stream>>>(e0, e1, cursor, ss0, ss1, E, N);
        xcvt_kernel<<<2048, 256, 0, stream>>>(x, Xbf, ((long)N * F) / 4);
    }

    const int nrb   = (N + GBM - 1) / GBM;   // 391 row blocks (TM=128)
    const int nrb64 = (N + 63) / 64;         // 782 row blocks (TM=64)

    auto run_layer = [&](const short* Ain, int DBsel, int Fin,
                         const float* Wk, const float* bk,
                         const float* Wq, const float* bq,
                         const float* Wv, const float* bv,
                         const float* arel, const float* mrel, const float* prel,
                         const float* Wa, const float* ba,
                         const float* gate, const short* skipHi,
                         short* outHi) {
        dim3 bg((Fin + 255) / 256, 768);   // [640,768) = fused WaT transpose
        build_wbigT_p<<<bg, 256, 0, stream>>>(Wq, bq, Wk, bk, Wv, bv,
                                              arel, mrel, Wa,
                                              WThi, WaThi, B640, Fin);
        int qb = (640 / GBN) * nrb;        // 1D grid, XCD-swizzled in-kernel
        if (DBsel) {
            // layer-1 QKV (K=512): TM=128 dbuf — best measured (83 us, R16)
            gemm_planes<1, 128><<<qb, 256, 0, stream>>>(Ain, Fin, WThi, Fin,
                B640, Qh, (short*)KVh, N, 640, Fin, 0, nullptr, nullptr);
        } else {
            // QKV 2/3 (K=128): single-buffer TM=128 — best measured (R14/R15)
            gemm_planes<0, 128><<<qb, 256, 0, stream>>>(Ain, Fin, WThi, Fin,
                B640, Qh, (short*)KVh, N, 640, Fin, 0, nullptr, nullptr);
        }

        node_attn_kernel<<<(N + 3) / 4, 256, 0, stream>>>(
            Qh, KVh, off0, ss0, off1, ss1, prel, ACChi, N);

        // out-GEMM (K=128): single-buffer TM=64 — best measured (R11..R15)
        gemm_planes<0, 64><<<nrb64, 256, 0, stream>>>(ACChi, 128, WaThi, 128,
            ba, nullptr, outHi, N, 128, 128,
            gate ? 3 : 2, gate, skipHi);
    };

    // layer 1 (bf16 x, K=512 -> dbuf TM=128) -> H1 plane
    run_layer(Xbf, 1, F, W_k1, b_k1, W_q1, b_q1, W_v1, b_v1,
              a_rel1, m_rel1, p_rel1, W_a1, b_a1,
              nullptr, nullptr, H1hi);
    // layer 2 (H1 plane, K=128 -> single-buffer, gated skip from H1) -> H2
    run_layer(H1hi, 0, HDIM, W_k23, b_k23, W_q23, b_q23, W_v23, b_v23,
              a_rel23, m_rel23, p_rel23, W_a23, b_a23,
              skip23, H1hi, H2hi);
    // layer 3 (H2 plane, gated skip from H2) -> H1 plane (reuse)
    run_layer(H2hi, 0, HDIM, W_k23 + 16384, b_k23 + 128, W_q23 + 16384, b_q23 + 128,
              W_v23 + 16384, b_v23 + 128, a_rel23 + 16384, m_rel23 + 16384,
              p_rel23 + 4, W_a23 + 16384, b_a23 + 128,
              skip23 + 1, H2hi, H1hi);

    // global mean pool (batch sorted)
    hipMemsetAsync(S, 0, (size_t)N_GRAPHS_C * HDIM * sizeof(float), stream);
    dim3 pg(N_GRAPHS_C, 8);
    pool_kernel<<<pg, HDIM, 0, stream>>>(H1hi, batch, S, N);
    pool_finalize<<<N_GRAPHS_C, HDIM, 0, stream>>>(S, batch, GM, N);

    // MLP
    {
        dim3 g1(128 / BN, 1);
        gemm_bias_kernel<<<g1, 256, 0, stream>>>(GM, 128, W_m1, 128, b_m1, M1, 128,
                                                 N_GRAPHS_C, 128, 1);
        dim3 g2(256 / BN, 1);
        gemm_bias_kernel<<<g2, 256, 0, stream>>>(M1, 128, W_m2, 256, b_m2,
                                                 (float*)d_out, 256, N_GRAPHS_C, 128, 0);
    }
}